// Round 8
// baseline (1081.487 us; speedup 1.0000x reference)
//
#include <hip/hip_runtime.h>

#define NB 20000
#define EB 320000
#define DIN 128
#define H1D 256
#define H2D 256
#define DOUTD 128
#define SCAN_BLOCKS ((NB + 255) / 256)   // 79

typedef __attribute__((ext_vector_type(4))) float fvec4;

__device__ inline float4 ntload4(const float* p) {
    fvec4 v = __builtin_nontemporal_load((const fvec4*)p);
    return make_float4(v.x, v.y, v.z, v.w);
}
__device__ inline void ntstore4(float* p, float4 v) {
    fvec4 t; t.x = v.x; t.y = v.y; t.z = v.z; t.w = v.w;
    __builtin_nontemporal_store(t, (fvec4*)p);
}

// ---------------------------------------------------------------------------
// CSR build: histogram -> parallel 3-phase scan -> dinv -> counting-sort
// scatter into int2{src, w_bits} edge records sorted by dst.
// ---------------------------------------------------------------------------

__global__ void zero_kernel(int* __restrict__ p, int n) {
    int t = blockIdx.x * blockDim.x + threadIdx.x;
    if (t < n) p[t] = 0;
}

__global__ void hist_kernel(const int* __restrict__ dst, int* __restrict__ bins) {
    int t = blockIdx.x * blockDim.x + threadIdx.x;
    if (t < EB) atomicAdd(&bins[dst[t]], 1);
}

__global__ __launch_bounds__(256) void scanA_kernel(const int* __restrict__ bins,
                                                    int* __restrict__ loc,
                                                    int* __restrict__ blksum) {
    __shared__ int s[256];
    int t = threadIdx.x;
    int i = blockIdx.x * 256 + t;
    int v = (i < NB) ? bins[i] : 0;
    s[t] = v;
    __syncthreads();
    for (int off = 1; off < 256; off <<= 1) {
        int u = (t >= off) ? s[t - off] : 0;
        __syncthreads();
        s[t] += u;
        __syncthreads();
    }
    if (i < NB) loc[i] = s[t] - v;
    if (t == 255) blksum[blockIdx.x] = s[255];
}

__global__ __launch_bounds__(128) void scanB_kernel(int* __restrict__ blksum) {
    __shared__ int s[128];
    int t = threadIdx.x;
    int v = (t < SCAN_BLOCKS) ? blksum[t] : 0;
    s[t] = v;
    __syncthreads();
    for (int off = 1; off < 128; off <<= 1) {
        int u = (t >= off) ? s[t - off] : 0;
        __syncthreads();
        s[t] += u;
        __syncthreads();
    }
    if (t < SCAN_BLOCKS) blksum[t] = s[t] - v;
}

__global__ __launch_bounds__(256) void scanC_kernel(const int* __restrict__ bins,
                                                    const int* __restrict__ loc,
                                                    const int* __restrict__ blksum,
                                                    int* __restrict__ rs,
                                                    int* __restrict__ cursor,
                                                    float* __restrict__ dinv) {
    int i = blockIdx.x * 256 + threadIdx.x;
    if (i < NB) {
        int r = loc[i] + blksum[blockIdx.x];
        rs[i] = r;
        cursor[i] = r;
        dinv[i] = rsqrtf((float)bins[i] + 1.0f);  // deg = in-degree + 1 (self loop)
    }
    if (i == 0) rs[NB] = EB;
}

__global__ void scatter_kernel(const int* __restrict__ src, const int* __restrict__ dst,
                               const float* __restrict__ dinv,
                               int* __restrict__ cursor, int2* __restrict__ edges) {
    int t = blockIdx.x * blockDim.x + threadIdx.x;
    if (t < EB) {
        int d = dst[t], s = src[t];
        int p = atomicAdd(&cursor[d], 1);
        edges[p] = make_int2(s, __float_as_int(dinv[s] * dinv[d]));
    }
}

// ---------------------------------------------------------------------------
// L2-resident sliced aggregation (per batch). A slice = 32 CONSECUTIVE floats
// of one node's row = exactly one 128B L2 line. F=128: 4 slices x 2 dst-node
// halves = 8 virtual slices; F=256: 8 slices. Virtual slice v is processed
// only by blocks whose DISPATCH blockIdx %8 == v -> all gathers of one XCD
// target a 20000x128B = 2.56 MB window, resident in its 4 MB L2.
// Edge walk: 32-lane half-wave per edge (one 128B load), 2 edges per step,
// 8-edge unroll -> 4 independent load chains. Wave-uniform bounds, rs carry.
// NTE: nontemporal edge records (used at F=256 where the 2.5 MB edge stream
// would overflow L2 alongside the slice). Output stores nontemporal.
// ---------------------------------------------------------------------------

template <int F, bool BIAS, bool PRELU, bool NTE>
__device__ void aggs_body(int a, int xcd,
                          const float* __restrict__ h, float* __restrict__ out,
                          const int* __restrict__ rs, const int2* __restrict__ edges,
                          const float* __restrict__ dinv, const float* __restrict__ bias,
                          const float* __restrict__ pa) {
    constexpr int NS = F / 32;            // slices per row: 4 / 8
    constexpr int NH = 8 / NS;            // dst-node halves: 2 / 1
    constexpr int CG = (F == 128) ? 125 : 250;
    constexpr int NPB = NB / NH / CG;     // 80 nodes per block
    constexpr int NPW = NPB / 4;          // 20 nodes per wave

    const int s32 = xcd & (NS - 1);
    const int half = xcd / NS;
    const int chunk = a >> 3;
    const int wid = threadIdx.x >> 6;
    const int lane = threadIdx.x & 63;
    const int li = lane & 31;             // float within slice
    const int eh = lane >> 5;             // which edge of the pair

    const float* gb = h + s32 * 32 + li;
    const float pav = PRELU ? *pa : 0.0f;
    const float bval = BIAS ? bias[s32 * 32 + li] : 0.0f;

    int n = half * (NB / NH) + chunk * NPB + wid * NPW;
    int e1 = __builtin_amdgcn_readfirstlane(rs[n]);
    for (int j = 0; j < NPW; ++j, ++n) {
        int e0 = e1;
        e1 = __builtin_amdgcn_readfirstlane(rs[n + 1]);
        float a0 = 0.f, a1 = 0.f, a2 = 0.f, a3 = 0.f;
        int e = e0;
        for (; e + 8 <= e1; e += 8) {
            int s0, s1, s2, s3;
            float w0, w1, w2, w3;
            if (NTE) {
                long long r0 = __builtin_nontemporal_load((const long long*)(edges + e + eh));
                long long r1 = __builtin_nontemporal_load((const long long*)(edges + e + 2 + eh));
                long long r2 = __builtin_nontemporal_load((const long long*)(edges + e + 4 + eh));
                long long r3 = __builtin_nontemporal_load((const long long*)(edges + e + 6 + eh));
                s0 = (int)r0; w0 = __int_as_float((int)(r0 >> 32));
                s1 = (int)r1; w1 = __int_as_float((int)(r1 >> 32));
                s2 = (int)r2; w2 = __int_as_float((int)(r2 >> 32));
                s3 = (int)r3; w3 = __int_as_float((int)(r3 >> 32));
            } else {
                int2 r0 = edges[e + eh], r1 = edges[e + 2 + eh];
                int2 r2 = edges[e + 4 + eh], r3 = edges[e + 6 + eh];
                s0 = r0.x; w0 = __int_as_float(r0.y);
                s1 = r1.x; w1 = __int_as_float(r1.y);
                s2 = r2.x; w2 = __int_as_float(r2.y);
                s3 = r3.x; w3 = __int_as_float(r3.y);
            }
            float t0 = gb[(size_t)s0 * F];
            float t1 = gb[(size_t)s1 * F];
            float t2 = gb[(size_t)s2 * F];
            float t3 = gb[(size_t)s3 * F];
            a0 = fmaf(t0, w0, a0);
            a1 = fmaf(t1, w1, a1);
            a2 = fmaf(t2, w2, a2);
            a3 = fmaf(t3, w3, a3);
        }
        for (; e + 2 <= e1; e += 2) {
            int2 r0 = edges[e + eh];
            a0 = fmaf(gb[(size_t)r0.x * F], __int_as_float(r0.y), a0);
        }
        if (e < e1) {  // one leftover edge; eh==1 lane contributes 0
            int my = e + eh;
            bool valid = (my < e1);
            int2 r0 = edges[valid ? my : e];
            float w = valid ? __int_as_float(r0.y) : 0.0f;
            a0 = fmaf(gb[(size_t)r0.x * F], w, a0);
        }
        float acc = (a0 + a1) + (a2 + a3);
        acc += __shfl_xor(acc, 32, 64);
        float dv = dinv[n];
        float ts = gb[(size_t)n * F];
        float r = fmaf(ts, dv * dv, acc);
        if (BIAS) r += bval;
        if (PRELU) r = (r >= 0.0f) ? r : pav * r;
        if (eh == 0)
            __builtin_nontemporal_store(r, out + (size_t)n * F + s32 * 32 + li);
    }
}

// ---------------------------------------------------------------------------
// FP32 GEMM body: C[M,Nc] = A[M,K] @ W[K,Nc] (+bias)(+prelu).
// 128x128 tile, BK=16, 256 threads, 16x4 microtile (64 FMA / 5 ds_read_b128).
// A-loads and C-stores NONTEMPORAL: A/C are streaming; keeps the co-resident
// agg blocks' L2 slice window intact in fat dispatches. W stays cached.
// ---------------------------------------------------------------------------
template <bool BIAS, bool PRELU>
__device__ void gemm_body(int gx, const float* __restrict__ A, int M, int K,
                          const float* __restrict__ W, int Nc,
                          const float* __restrict__ bias, const float* __restrict__ pa,
                          float* __restrict__ C, int mt) {
    __shared__ alignas(16) float As[16][132];
    __shared__ alignas(16) float Bs[16][132];
    int t = threadIdx.x;
    int bm = (gx % mt) * 128;
    int bn = (gx / mt) * 128;
    int tx = t & 31, ty = t >> 5;
    int m0 = ty * 16, n0 = tx * 4;
    int ar = t >> 2, ac4 = (t & 3) * 4;   // A rows ar, ar+64; k-cols ac4..+3
    int bk = t >> 4, bc4 = (t & 15) * 4;  // B row bk, cols bc4, bc4+64

    float acc[16][4] = {};

    for (int k0 = 0; k0 < K; k0 += 16) {
        float4 a0 = make_float4(0.f, 0.f, 0.f, 0.f), a1 = a0;
        int r0 = bm + ar, r1 = bm + ar + 64;
        if (r0 < M) a0 = ntload4(&A[(size_t)r0 * K + k0 + ac4]);
        if (r1 < M) a1 = ntload4(&A[(size_t)r1 * K + k0 + ac4]);
        As[ac4 + 0][ar] = a0.x; As[ac4 + 1][ar] = a0.y;
        As[ac4 + 2][ar] = a0.z; As[ac4 + 3][ar] = a0.w;
        As[ac4 + 0][ar + 64] = a1.x; As[ac4 + 1][ar + 64] = a1.y;
        As[ac4 + 2][ar + 64] = a1.z; As[ac4 + 3][ar + 64] = a1.w;
        float4 b0 = *(const float4*)&W[(size_t)(k0 + bk) * Nc + bn + bc4];
        float4 b1 = *(const float4*)&W[(size_t)(k0 + bk) * Nc + bn + bc4 + 64];
        *(float4*)&Bs[bk][bc4] = b0;
        *(float4*)&Bs[bk][bc4 + 64] = b1;
        __syncthreads();
#pragma unroll
        for (int k = 0; k < 16; ++k) {
            float4 av0 = *(const float4*)&As[k][m0];
            float4 av1 = *(const float4*)&As[k][m0 + 4];
            float4 av2 = *(const float4*)&As[k][m0 + 8];
            float4 av3 = *(const float4*)&As[k][m0 + 12];
            float4 bv = *(const float4*)&Bs[k][n0];
            float a_[16] = {av0.x, av0.y, av0.z, av0.w, av1.x, av1.y, av1.z, av1.w,
                            av2.x, av2.y, av2.z, av2.w, av3.x, av3.y, av3.z, av3.w};
            float b_[4] = {bv.x, bv.y, bv.z, bv.w};
#pragma unroll
            for (int i = 0; i < 16; ++i)
#pragma unroll
                for (int j = 0; j < 4; ++j)
                    acc[i][j] = fmaf(a_[i], b_[j], acc[i][j]);
        }
        __syncthreads();
    }

    float pav = 0.0f;
    if (PRELU) pav = *pa;
#pragma unroll
    for (int i = 0; i < 16; ++i) {
        int row = bm + m0 + i;
        if (row < M) {
            float v[4];
#pragma unroll
            for (int j = 0; j < 4; ++j) {
                float x = acc[i][j];
                if (BIAS) x += bias[bn + n0 + j];
                if (PRELU) x = (x >= 0.0f) ? x : pav * x;
                v[j] = x;
            }
            ntstore4(&C[(size_t)row * Nc + bn + n0], make_float4(v[0], v[1], v[2], v[3]));
        }
    }
}

// ---------------------------------------------------------------------------
// Wrappers. Fat kernel: gemm blocks first (bx < ng), agg tail. The agg's
// XCD-slice binding uses the DISPATCH blockIdx (&7) so %8 still maps to XCDs;
// (chunk, xcd) coverage stays bijective for any ng.
// ---------------------------------------------------------------------------

template <int F, bool BIAS, bool PRELU, bool NTE>
__global__ __launch_bounds__(256) void agg_kernel(
    const float* __restrict__ h, float* __restrict__ out,
    const int* __restrict__ rs, const int2* __restrict__ edges,
    const float* __restrict__ dinv, const float* __restrict__ bias,
    const float* __restrict__ pa) {
    aggs_body<F, BIAS, PRELU, NTE>(blockIdx.x, blockIdx.x & 7, h, out, rs, edges,
                                   dinv, bias, pa);
}

template <bool BIAS, bool PRELU>
__global__ __launch_bounds__(256) void gemm_kernel(
    const float* __restrict__ A, int M, int K, const float* __restrict__ W, int Nc,
    const float* __restrict__ bias, const float* __restrict__ pa,
    float* __restrict__ C, int mt) {
    gemm_body<BIAS, PRELU>(blockIdx.x, A, M, K, W, Nc, bias, pa, C, mt);
}

template <int AF, bool AB, bool AP, bool ANTE, bool GB_, bool GP>
__global__ __launch_bounds__(256) void fat_kernel(
    const float* __restrict__ A, int K, const float* __restrict__ W, int Nc,
    const float* __restrict__ gbias, float* __restrict__ C, int mt, int ng,
    const float* __restrict__ ah, float* __restrict__ aout,
    const int* __restrict__ rs, const int2* __restrict__ edges,
    const float* __restrict__ dinv, const float* __restrict__ abias,
    const float* __restrict__ pa) {
    int bx = blockIdx.x;
    if (bx < ng) {
        gemm_body<GB_, GP>(bx, A, NB, K, W, Nc, gbias, pa, C, mt);
    } else {
        aggs_body<AF, AB, AP, ANTE>(bx - ng, bx & 7, ah, aout, rs, edges, dinv,
                                    abias, pa);
    }
}

// ---------------------------------------------------------------------------

static inline char* carve(char*& p, size_t bytes) {
    char* r = p;
    p += (bytes + 255) & ~(size_t)255;
    return r;
}

extern "C" void kernel_launch(void* const* d_in, const int* in_sizes, int n_in,
                              void* d_out, int out_size, void* d_ws, size_t ws_size,
                              hipStream_t stream) {
    const float* X  = (const float*)d_in[0];
    const float* W1 = (const float*)d_in[1];
    const float* b1 = (const float*)d_in[2];
    const float* W2 = (const float*)d_in[3];
    const float* b2 = (const float*)d_in[4];
    const float* W3 = (const float*)d_in[5];
    const float* b3 = (const float*)d_in[6];
    const float* pa = (const float*)d_in[7];
    const int* ei   = (const int*)d_in[8];
    const int* src = ei;
    const int* dst = ei + EB;
    float* out = (float*)d_out;

    char* p = (char*)d_ws;
    int* bins    = (int*)carve(p, NB * sizeof(int));
    int* loc     = (int*)carve(p, NB * sizeof(int));
    int* blksum  = (int*)carve(p, 128 * sizeof(int));
    int* rs      = (int*)carve(p, (NB + 1) * sizeof(int));
    int* cursor  = (int*)carve(p, NB * sizeof(int));
    int2* edges  = (int2*)carve(p, EB * sizeof(int2));
    float* dinv  = (float*)carve(p, NB * sizeof(float));
    float* P0 = (float*)carve(p, (size_t)NB * 256 * sizeof(float));
    float* Q0 = (float*)carve(p, (size_t)NB * 256 * sizeof(float));
    float* P1 = (float*)carve(p, (size_t)NB * 256 * sizeof(float));
    float* Q1 = (float*)carve(p, (size_t)NB * 256 * sizeof(float));

    const float* X0 = X;
    const float* X1 = X + (size_t)NB * DIN;
    float* out0 = out;
    float* out1 = out + (size_t)NB * DOUTD;

    // --- CSR build ---
    zero_kernel<<<SCAN_BLOCKS, 256, 0, stream>>>(bins, NB);
    hist_kernel<<<(EB + 255) / 256, 256, 0, stream>>>(dst, bins);
    scanA_kernel<<<SCAN_BLOCKS, 256, 0, stream>>>(bins, loc, blksum);
    scanB_kernel<<<1, 128, 0, stream>>>(blksum);
    scanC_kernel<<<SCAN_BLOCKS, 256, 0, stream>>>(bins, loc, blksum, rs, cursor, dinv);
    scatter_kernel<<<(EB + 255) / 256, 256, 0, stream>>>(src, dst, dinv, cursor, edges);

    const int MT = (NB + 127) / 128;        // 157
    const int NG_256 = MT * (256 / 128);    // 314
    const int NG_128 = MT * (128 / 128);    // 157
    const int AGG128 = 8 * 125;             // 1000 blocks
    const int AGG256 = 8 * 250;             // 2000 blocks

    // Per-batch chain: A1 -> G1 -> G2 -> A2 -> G3 -> A3, staggered by 1 stage.

    // D1: A1(b0): X0 --agg--> P0 [F=128]
    agg_kernel<128, false, false, false><<<AGG128, 256, 0, stream>>>(
        X0, P0, rs, edges, dinv, nullptr, nullptr);

    // D2: G1(b0): P0 @ W1 (+b1,prelu) -> Q0   ||   A1(b1): X1 -> P1
    fat_kernel<128, false, false, false, true, true><<<NG_256 + AGG128, 256, 0, stream>>>(
        P0, DIN, W1, H1D, b1, Q0, MT, NG_256,
        X1, P1, rs, edges, dinv, nullptr, pa);

    // D3: G2(b0): Q0 @ W2 -> P0   ;   G1(b1): P1 @ W1 (+b1,prelu) -> Q1
    gemm_kernel<false, false><<<NG_256, 256, 0, stream>>>(
        Q0, NB, H1D, W2, H2D, nullptr, pa, P0, MT);
    gemm_kernel<true, true><<<NG_256, 256, 0, stream>>>(
        P1, NB, DIN, W1, H1D, b1, pa, Q1, MT);

    // D4: G2(b1): Q1 @ W2 -> P1   ||   A2(b0): P0 --agg(+b2,prelu)--> Q0 [F=256]
    fat_kernel<256, true, true, true, false, false><<<NG_256 + AGG256, 256, 0, stream>>>(
        Q1, H1D, W2, H2D, nullptr, P1, MT, NG_256,
        P0, Q0, rs, edges, dinv, b2, pa);

    // D5: G3(b0): Q0 @ W3 -> P0   ||   A2(b1): P1 --agg(+b2,prelu)--> Q1 [F=256]
    fat_kernel<256, true, true, true, false, false><<<NG_128 + AGG256, 256, 0, stream>>>(
        Q0, H2D, W3, DOUTD, nullptr, P0, MT, NG_128,
        P1, Q1, rs, edges, dinv, b2, pa);

    // D6: G3(b1): Q1 @ W3 -> P1   ||   A3(b0): P0 --agg(+b3)--> out0 [F=128]
    fat_kernel<128, true, false, false, false, false><<<NG_128 + AGG128, 256, 0, stream>>>(
        Q1, H2D, W3, DOUTD, nullptr, P1, MT, NG_128,
        P0, out0, rs, edges, dinv, b3, pa);

    // D7: A3(b1): P1 --agg(+b3)--> out1 [F=128]
    agg_kernel<128, true, false, false><<<AGG128, 256, 0, stream>>>(
        P1, out1, rs, edges, dinv, b3, nullptr);
}

// Round 9
// 490.730 us; speedup vs baseline: 2.2038x; 2.2038x over previous
//
#include <hip/hip_runtime.h>

#define NB 20000
#define EB 320000
#define DIN 128
#define H1D 256
#define H2D 256
#define DOUTD 128
#define SCAN_BLOCKS ((NB + 255) / 256)   // 79

// ---------------------------------------------------------------------------
// CSR build: histogram -> parallel 3-phase scan -> dinv -> counting-sort
// scatter into int2{src, w_bits} edge records sorted by dst.
// ---------------------------------------------------------------------------

__global__ void zero_kernel(int* __restrict__ p, int n) {
    int t = blockIdx.x * blockDim.x + threadIdx.x;
    if (t < n) p[t] = 0;
}

__global__ void hist_kernel(const int* __restrict__ dst, int* __restrict__ bins) {
    int t = blockIdx.x * blockDim.x + threadIdx.x;
    if (t < EB) atomicAdd(&bins[dst[t]], 1);
}

__global__ __launch_bounds__(256) void scanA_kernel(const int* __restrict__ bins,
                                                    int* __restrict__ loc,
                                                    int* __restrict__ blksum) {
    __shared__ int s[256];
    int t = threadIdx.x;
    int i = blockIdx.x * 256 + t;
    int v = (i < NB) ? bins[i] : 0;
    s[t] = v;
    __syncthreads();
    for (int off = 1; off < 256; off <<= 1) {
        int u = (t >= off) ? s[t - off] : 0;
        __syncthreads();
        s[t] += u;
        __syncthreads();
    }
    if (i < NB) loc[i] = s[t] - v;
    if (t == 255) blksum[blockIdx.x] = s[255];
}

__global__ __launch_bounds__(128) void scanB_kernel(int* __restrict__ blksum) {
    __shared__ int s[128];
    int t = threadIdx.x;
    int v = (t < SCAN_BLOCKS) ? blksum[t] : 0;
    s[t] = v;
    __syncthreads();
    for (int off = 1; off < 128; off <<= 1) {
        int u = (t >= off) ? s[t - off] : 0;
        __syncthreads();
        s[t] += u;
        __syncthreads();
    }
    if (t < SCAN_BLOCKS) blksum[t] = s[t] - v;
}

__global__ __launch_bounds__(256) void scanC_kernel(const int* __restrict__ bins,
                                                    const int* __restrict__ loc,
                                                    const int* __restrict__ blksum,
                                                    int* __restrict__ rs,
                                                    int* __restrict__ cursor,
                                                    float* __restrict__ dinv) {
    int i = blockIdx.x * 256 + threadIdx.x;
    if (i < NB) {
        int r = loc[i] + blksum[blockIdx.x];
        rs[i] = r;
        cursor[i] = r;
        dinv[i] = rsqrtf((float)bins[i] + 1.0f);  // deg = in-degree + 1 (self loop)
    }
    if (i == 0) rs[NB] = EB;
}

__global__ void scatter_kernel(const int* __restrict__ src, const int* __restrict__ dst,
                               const float* __restrict__ dinv,
                               int* __restrict__ cursor, int2* __restrict__ edges) {
    int t = blockIdx.x * blockDim.x + threadIdx.x;
    if (t < EB) {
        int d = dst[t], s = src[t];
        int p = atomicAdd(&cursor[d], 1);
        edges[p] = make_int2(s, __float_as_int(dinv[s] * dinv[d]));
    }
}

// ---------------------------------------------------------------------------
// Sliced aggregation v2 (L2-resident + repaired issue structure).
// A virtual slice = 32 consecutive floats of ONE batch's row = one 128B L2
// line. 8 virtual slices per dispatch (F=128: 4 col-slices x 2 batches;
// F=256: phase p covers col-slices 4p..4p+3 x 2 batches, 2 dispatches).
// Slice ss is processed only by blocks with blockIdx%8==ss -> under
// round-robin dispatch each XCD gathers from a 20000x128B = 2.56 MB window,
// resident in its private 4 MB L2 (confirmed: FETCH 315->51 MB in R8).
// R8's execution fixes: CACHED edge loads (no nontemporal), 5 nodes/wave
// (8000 blocks x 4 waves = 32000 waves of TLP), standalone kernel (low VGPR).
// Edge walk: 32-lane half per edge (one line), 2 edges/step, 8-edge unroll
// -> 4 independent record+gather chains. All strides are powers of 2.
// ---------------------------------------------------------------------------

template <int F, bool SPLIT_IN, bool SPLIT_OUT, bool BIAS, bool PRELU>
__global__ __launch_bounds__(256) void aggv_kernel(
    const float* __restrict__ h, float* __restrict__ out,
    const int* __restrict__ rs, const int2* __restrict__ edges,
    const float* __restrict__ dinv, const float* __restrict__ bias,
    const float* __restrict__ pa, int phase) {
    const int ss = blockIdx.x & 7;        // virtual slice -> XCD
    const int chunk = blockIdx.x >> 3;    // [0, 1000)
    const int wid = threadIdx.x >> 6;
    const int lane = threadIdx.x & 63;
    const int li = lane & 31;             // float within the 32-float slice
    const int eh = lane >> 5;             // which edge of the step-pair
    const int b = ss >> 2;                // batch
    const int c32 = (ss & 3) + phase * 4; // 32-float column block
    const int fo = c32 * 32 + li;

    constexpr size_t GS = SPLIT_IN ? F : 2 * F;   // power of 2
    constexpr size_t OS = SPLIT_OUT ? F : 2 * F;
    const float* gb = h + (SPLIT_IN ? (size_t)b * NB * F : (size_t)b * F) + fo;
    float* ob = out + (SPLIT_OUT ? (size_t)b * NB * F : (size_t)b * F) + fo;

    const float pav = PRELU ? *pa : 0.0f;
    const float bval = BIAS ? bias[fo] : 0.0f;

    int n = chunk * 20 + wid * 5;         // 5 nodes per wave, no tails
    int e1n = __builtin_amdgcn_readfirstlane(rs[n]);
    for (int j = 0; j < 5; ++j, ++n) {
        int e0 = e1n;
        e1n = __builtin_amdgcn_readfirstlane(rs[n + 1]);
        int e1 = e1n;
        float a0 = 0.f, a1 = 0.f, a2 = 0.f, a3 = 0.f;
        int e = e0;
        for (; e + 8 <= e1; e += 8) {
            int2 r0 = edges[e + eh];
            int2 r1 = edges[e + 2 + eh];
            int2 r2 = edges[e + 4 + eh];
            int2 r3 = edges[e + 6 + eh];
            float t0 = gb[(size_t)r0.x * GS];
            float t1 = gb[(size_t)r1.x * GS];
            float t2 = gb[(size_t)r2.x * GS];
            float t3 = gb[(size_t)r3.x * GS];
            a0 = fmaf(t0, __int_as_float(r0.y), a0);
            a1 = fmaf(t1, __int_as_float(r1.y), a1);
            a2 = fmaf(t2, __int_as_float(r2.y), a2);
            a3 = fmaf(t3, __int_as_float(r3.y), a3);
        }
        for (; e + 2 <= e1; e += 2) {
            int2 r0 = edges[e + eh];
            a0 = fmaf(gb[(size_t)r0.x * GS], __int_as_float(r0.y), a0);
        }
        if (e < e1) {  // single leftover edge; eh==1 lanes contribute 0
            int my = e + eh;
            bool valid = (my < e1);
            int2 r0 = edges[valid ? my : e];
            float w = valid ? __int_as_float(r0.y) : 0.0f;
            a0 = fmaf(gb[(size_t)r0.x * GS], w, a0);
        }
        float acc = (a0 + a1) + (a2 + a3);
        acc += __shfl_xor(acc, 32, 64);
        float dv = dinv[n];
        float r = fmaf(gb[(size_t)n * GS], dv * dv, acc);
        if (BIAS) r += bval;
        if (PRELU) r = (r >= 0.0f) ? r : pav * r;
        if (eh == 0) ob[(size_t)n * OS] = r;
    }
}

// ---------------------------------------------------------------------------
// FP32 GEMM: C[M,Nc] = A[M,K] @ W[K,Nc] (+bias)(+prelu).
// 128x64 tile, BK=16, 256 threads, 8x4 microtile (R4's proven version).
// ---------------------------------------------------------------------------
template <bool BIAS, bool PRELU>
__global__ __launch_bounds__(256) void gemm_kernel(const float* __restrict__ A, int M, int K,
                                                   const float* __restrict__ W, int Nc,
                                                   const float* __restrict__ bias,
                                                   const float* __restrict__ pa,
                                                   float* __restrict__ C) {
    __shared__ alignas(16) float As[16][132];
    __shared__ alignas(16) float Bs[16][68];
    int t = threadIdx.x;
    int bm = blockIdx.x * 128;
    int bn = blockIdx.y * 64;
    int tx = t & 15, ty = t >> 4;
    int m0 = ty * 8, n0 = tx * 4;
    int ar = t >> 2, ac4 = (t & 3) * 4;
    int br = t >> 4, bc4 = (t & 15) * 4;

    float acc[8][4] = {};

    for (int k0 = 0; k0 < K; k0 += 16) {
        float4 a0 = make_float4(0.f, 0.f, 0.f, 0.f), a1 = a0;
        int r0 = bm + ar, r1 = bm + ar + 64;
        if (r0 < M) a0 = *(const float4*)&A[(size_t)r0 * K + k0 + ac4];
        if (r1 < M) a1 = *(const float4*)&A[(size_t)r1 * K + k0 + ac4];
        As[ac4 + 0][ar] = a0.x; As[ac4 + 1][ar] = a0.y;
        As[ac4 + 2][ar] = a0.z; As[ac4 + 3][ar] = a0.w;
        As[ac4 + 0][ar + 64] = a1.x; As[ac4 + 1][ar + 64] = a1.y;
        As[ac4 + 2][ar + 64] = a1.z; As[ac4 + 3][ar + 64] = a1.w;
        float4 bv = *(const float4*)&W[(size_t)(k0 + br) * Nc + bn + bc4];
        *(float4*)&Bs[br][bc4] = bv;
        __syncthreads();
#pragma unroll
        for (int k = 0; k < 16; ++k) {
            float4 av0 = *(const float4*)&As[k][m0];
            float4 av1 = *(const float4*)&As[k][m0 + 4];
            float4 bv4 = *(const float4*)&Bs[k][n0];
            float a_[8] = {av0.x, av0.y, av0.z, av0.w, av1.x, av1.y, av1.z, av1.w};
            float b_[4] = {bv4.x, bv4.y, bv4.z, bv4.w};
#pragma unroll
            for (int i = 0; i < 8; ++i)
#pragma unroll
                for (int j = 0; j < 4; ++j)
                    acc[i][j] = fmaf(a_[i], b_[j], acc[i][j]);
        }
        __syncthreads();
    }

    float pav = 0.0f;
    if (PRELU) pav = *pa;
#pragma unroll
    for (int i = 0; i < 8; ++i) {
        int row = bm + m0 + i;
        if (row < M) {
            float v[4];
#pragma unroll
            for (int j = 0; j < 4; ++j) {
                float x = acc[i][j];
                if (BIAS) x += bias[bn + n0 + j];
                if (PRELU) x = (x >= 0.0f) ? x : pav * x;
                v[j] = x;
            }
            *(float4*)&C[(size_t)row * Nc + bn + n0] = make_float4(v[0], v[1], v[2], v[3]);
        }
    }
}

// ---------------------------------------------------------------------------

static inline char* carve(char*& p, size_t bytes) {
    char* r = p;
    p += (bytes + 255) & ~(size_t)255;
    return r;
}

extern "C" void kernel_launch(void* const* d_in, const int* in_sizes, int n_in,
                              void* d_out, int out_size, void* d_ws, size_t ws_size,
                              hipStream_t stream) {
    const float* X  = (const float*)d_in[0];
    const float* W1 = (const float*)d_in[1];
    const float* b1 = (const float*)d_in[2];
    const float* W2 = (const float*)d_in[3];
    const float* b2 = (const float*)d_in[4];
    const float* W3 = (const float*)d_in[5];
    const float* b3 = (const float*)d_in[6];
    const float* pa = (const float*)d_in[7];
    const int* ei   = (const int*)d_in[8];
    const int* src = ei;
    const int* dst = ei + EB;
    float* out = (float*)d_out;

    char* p = (char*)d_ws;
    int* bins    = (int*)carve(p, NB * sizeof(int));
    int* loc     = (int*)carve(p, NB * sizeof(int));
    int* blksum  = (int*)carve(p, 128 * sizeof(int));
    int* rs      = (int*)carve(p, (NB + 1) * sizeof(int));
    int* cursor  = (int*)carve(p, NB * sizeof(int));
    int2* edges  = (int2*)carve(p, EB * sizeof(int2));
    float* dinv  = (float*)carve(p, NB * sizeof(float));
    float* bufA  = (float*)carve(p, (size_t)2 * NB * 256 * sizeof(float));
    float* bufB  = (float*)carve(p, (size_t)2 * NB * 256 * sizeof(float));

    const int M = 2 * NB;                  // batch-fused rows [node*2+b][F]
    const int AGGV = 1000 * 8;             // 1000 chunks x 8 slices

    // --- CSR build ---
    zero_kernel<<<SCAN_BLOCKS, 256, 0, stream>>>(bins, NB);
    hist_kernel<<<(EB + 255) / 256, 256, 0, stream>>>(dst, bins);
    scanA_kernel<<<SCAN_BLOCKS, 256, 0, stream>>>(bins, loc, blksum);
    scanB_kernel<<<1, 128, 0, stream>>>(blksum);
    scanC_kernel<<<SCAN_BLOCKS, 256, 0, stream>>>(bins, loc, blksum, rs, cursor, dinv);
    scatter_kernel<<<(EB + 255) / 256, 256, 0, stream>>>(src, dst, dinv, cursor, edges);

    // A1: X (batch-split) --agg--> bufA (interleaved) [F=128]
    aggv_kernel<128, true, false, false, false><<<AGGV, 256, 0, stream>>>(
        X, bufA, rs, edges, dinv, nullptr, nullptr, 0);

    // G1: bufA @ W1 (+b1, prelu) -> bufB   [M=40000, K=128, N=256]
    gemm_kernel<true, true><<<dim3((M + 127) / 128, H1D / 64), 256, 0, stream>>>(
        bufA, M, DIN, W1, H1D, b1, pa, bufB);

    // G2: bufB @ W2 -> bufA                [K=256, N=256]
    gemm_kernel<false, false><<<dim3((M + 127) / 128, H2D / 64), 256, 0, stream>>>(
        bufB, M, H1D, W2, H2D, nullptr, nullptr, bufA);

    // A2: bufA --agg(+b2, prelu)--> bufB [F=256], two phases (cols 0-127, 128-255)
    aggv_kernel<256, false, false, true, true><<<AGGV, 256, 0, stream>>>(
        bufA, bufB, rs, edges, dinv, b2, pa, 0);
    aggv_kernel<256, false, false, true, true><<<AGGV, 256, 0, stream>>>(
        bufA, bufB, rs, edges, dinv, b2, pa, 1);

    // G3: bufB @ W3 -> bufA                [K=256, N=128]
    gemm_kernel<false, false><<<dim3((M + 127) / 128, DOUTD / 64), 256, 0, stream>>>(
        bufB, M, H2D, W3, DOUTD, nullptr, nullptr, bufA);

    // A3: bufA --agg(+b3)--> out (batch-split) [F=128]
    aggv_kernel<128, false, true, true, false><<<AGGV, 256, 0, stream>>>(
        bufA, out, rs, edges, dinv, b3, nullptr, 0);
}